// Round 4
// baseline (198.136 us; speedup 1.0000x reference)
//
#include <hip/hip_runtime.h>
#include <cstdint>

typedef __attribute__((ext_vector_type(8))) short short8;
typedef __attribute__((ext_vector_type(4))) float f32x4;

#define LOG2E 1.44269504088896340736f

static __device__ __forceinline__ float bf2f(unsigned short u) {
    union { unsigned int i; float f; } v; v.i = ((unsigned int)u) << 16; return v.f;
}
static __device__ __forceinline__ unsigned short f2bf(float f) {
    union { float f; unsigned int i; } v; v.f = f;
    unsigned int r = v.i + 0x7FFF + ((v.i >> 16) & 1);
    return (unsigned short)(r >> 16);
}

// ---------------- K1: fp32 -> bf16 convert (x, Wq, Wk, Wv, Wo) ----------------
__global__ __launch_bounds__(256) void k_convert(
    const float* __restrict__ x, const float* __restrict__ wq,
    const float* __restrict__ wk, const float* __restrict__ wv,
    const float* __restrict__ wo, unsigned short* __restrict__ dst) {
    long t = (long)blockIdx.x * 256 + threadIdx.x;
    long base = t * 4;
    const long NX = 2097152, NW = 1048576;
    const float* src; long off;
    if (base < NX)            { src = x;  off = base; }
    else if (base < NX + NW)  { src = wq; off = base - NX; }
    else if (base < NX + 2*NW){ src = wk; off = base - NX - NW; }
    else if (base < NX + 3*NW){ src = wv; off = base - NX - 2*NW; }
    else                      { src = wo; off = base - NX - 3*NW; }
    float4 v = *(const float4*)(src + off);
    ushort4 o;
    o.x = f2bf(v.x); o.y = f2bf(v.y); o.z = f2bf(v.z); o.w = f2bf(v.w);
    *(ushort4*)(dst + base) = o;
}

// ---------------- K2: bias materialization, MFMA-fragment tile layout ---------
// Tile (b,h,ti,tj): rows i0=ti*16..+15, cols j0=tj*64..+63.
// Storage: tile base = ((bh*64+ti)*16+tj)*1024 elements; within tile,
// lane (g,c) owns 16 contiguous values at lane*16: idx = rr*4+jj for
// value (row i0+g*4+rr, col j0+c+16*jj). Matches 16x16x32 MFMA C layout.
__global__ __launch_bounds__(256) void k_bias(
    const float* __restrict__ Eidx, const float* __restrict__ Ebar,
    const float* __restrict__ Epos, const float* __restrict__ Eoct,
    const float* __restrict__ Esemi,
    const int* __restrict__ barm, const int* __restrict__ posm,
    const int* __restrict__ octm, const int* __restrict__ semim,
    unsigned short* __restrict__ biasg) {
    int bid = blockIdx.x;
    int tj = bid & 15, ti = (bid >> 4) & 63, b = bid >> 10;
    int i0 = ti * 16, j0 = tj * 64;
    if (j0 > i0 + 15) return;   // strictly-causal-masked tile: never read

    __shared__ float tbl[2416];          // Ebar(272) Epos(1536) Eoct(400) Esemi(208)
    __shared__ int   pk[16 * 65];        // packed indices, pad 65 (bank-safe)
    __shared__ float eidx_s[80 * 17];    // E_idx slice, pad 17 (bank-safe)

    int t = threadIdx.x;
    for (int i = t; i < 272;  i += 256) tbl[i]        = Ebar[i];
    for (int i = t; i < 1536; i += 256) tbl[272 + i]  = Epos[i];
    for (int i = t; i < 400;  i += 256) tbl[1808 + i] = Eoct[i];
    for (int i = t; i < 208;  i += 256) tbl[2208 + i] = Esemi[i];

    int rel_lo = i0 - j0 - 63; if (rel_lo < 0) rel_lo = 0;
    int rel_hi = i0 + 15 - j0;
    int nrel = rel_hi - rel_lo + 1;         // <= 79
    for (int idx = t; idx < nrel * 16; idx += 256) {
        int rr = idx >> 4, hh = idx & 15;
        eidx_s[rr * 17 + hh] = Eidx[(rel_lo + rr) * 16 + hh];
    }
    #pragma unroll
    for (int cc = 0; cc < 4; cc++) {
        int cell = t + cc * 256;
        int i = i0 + (cell >> 6), j = j0 + (cell & 63);
        long ij = ((long)b << 20) + ((long)i << 10) + j;
        int v = (barm[ij] + 1) | ((posm[ij] + 1) << 5) |
                ((octm[ij] + 1) << 12) | ((semim[ij] + 1) << 17);
        pk[(cell >> 6) * 65 + (cell & 63)] = v;
    }
    __syncthreads();

    int lane = t & 63, hq = t >> 6;
    int g = lane >> 4, c = lane & 15;
    // h-independent per-slot data, hoisted
    int pks[4][4], roff[4][4];
    #pragma unroll
    for (int rr = 0; rr < 4; rr++) {
        #pragma unroll
        for (int jj = 0; jj < 4; jj++) {
            int i = i0 + g * 4 + rr, j = j0 + c + 16 * jj;
            int rel = i - j; if (rel < 0) rel = 0;
            roff[rr][jj] = (rel - rel_lo) * 17;
            pks[rr][jj]  = pk[(g * 4 + rr) * 65 + c + 16 * jj];
        }
    }
    #pragma unroll
    for (int xx = 0; xx < 4; xx++) {
        int hh = hq + xx * 4;
        short8 o0v, o1v;
        #pragma unroll
        for (int rr = 0; rr < 4; rr++) {
            #pragma unroll
            for (int jj = 0; jj < 4; jj++) {
                int p = pks[rr][jj];
                float v = eidx_s[roff[rr][jj] + hh]
                        + tbl[(p & 31) * 16 + hh]
                        + tbl[272  + ((p >> 5)  & 127) * 16 + hh]
                        + tbl[1808 + ((p >> 12) & 31)  * 16 + hh]
                        + tbl[2208 + ((p >> 17) & 15)  * 16 + hh];
                unsigned short bv = f2bf(v * 0.125f);
                int idx = rr * 4 + jj;
                if (idx < 8) o0v[idx] = (short)bv; else o1v[idx - 8] = (short)bv;
            }
        }
        unsigned short* dst = biasg +
            ((((long)(b * 16 + hh) * 64 + ti) * 16 + tj) << 10) + lane * 16;
        *(short8*)dst       = o0v;
        *(short8*)(dst + 8) = o1v;
    }
}

// ---------------- K3/K5: bf16 GEMM  C[M][N] = A[M][1024] * B[N][1024]^T -------
__global__ __launch_bounds__(256) void k_gemm(
    const unsigned short* __restrict__ A,
    const unsigned short* __restrict__ B0, const unsigned short* __restrict__ B1,
    const unsigned short* __restrict__ B2,
    unsigned short* __restrict__ qd, unsigned short* __restrict__ kd,
    unsigned short* __restrict__ vtd, float* __restrict__ outf, int mode) {
    __shared__ unsigned short As[64][72];
    __shared__ unsigned short Bs[64][72];
    int md = (mode < 0) ? (int)blockIdx.z : mode;
    const unsigned short* B = (md == 1) ? B1 : (md == 2) ? B2 : B0;
    int m0 = blockIdx.x * 64, n0 = blockIdx.y * 64;
    int t = threadIdx.x;
    int w = t >> 6, lane = t & 63, g = lane >> 4, c = lane & 15;
    int srow = t >> 2, scg = t & 3;
    const int K = 1024;
    f32x4 zero = {0.f, 0.f, 0.f, 0.f};
    f32x4 acc[4];
    acc[0] = zero; acc[1] = zero; acc[2] = zero; acc[3] = zero;

    for (int k0 = 0; k0 < K; k0 += 64) {
        __syncthreads();
        *(short8*)&As[srow][scg * 16]     = *(const short8*)(A + (long)(m0 + srow) * K + k0 + scg * 16);
        *(short8*)&As[srow][scg * 16 + 8] = *(const short8*)(A + (long)(m0 + srow) * K + k0 + scg * 16 + 8);
        *(short8*)&Bs[srow][scg * 16]     = *(const short8*)(B + (long)(n0 + srow) * K + k0 + scg * 16);
        *(short8*)&Bs[srow][scg * 16 + 8] = *(const short8*)(B + (long)(n0 + srow) * K + k0 + scg * 16 + 8);
        __syncthreads();
        #pragma unroll
        for (int kk = 0; kk < 2; kk++) {
            short8 a = *(const short8*)&As[w * 16 + c][kk * 32 + g * 8];
            #pragma unroll
            for (int jc = 0; jc < 4; jc++) {
                short8 bf = *(const short8*)&Bs[jc * 16 + c][kk * 32 + g * 8];
                acc[jc] = __builtin_amdgcn_mfma_f32_16x16x32_bf16(a, bf, acc[jc], 0, 0, 0);
            }
        }
    }

    if (md <= 1) {
        unsigned short* dst = (md == 0) ? qd : kd;
        float scale = (md == 0) ? 0.125f : 1.0f;
        #pragma unroll
        for (int r = 0; r < 4; r++) {
            int mm = m0 + w * 16 + g * 4 + r;
            int bb = mm >> 10, ii = mm & 1023;
            #pragma unroll
            for (int jc = 0; jc < 4; jc++) {
                int nn = n0 + jc * 16 + c;
                int hh = nn >> 6, dd = nn & 63;
                dst[(((long)(bb * 16 + hh) << 10) + ii) * 64 + dd] = f2bf(acc[jc][r] * scale);
            }
        }
    } else if (md == 2) {
        int mm0 = m0 + w * 16 + g * 4;
        int bb = mm0 >> 10, ii = mm0 & 1023;
        #pragma unroll
        for (int jc = 0; jc < 4; jc++) {
            int nn = n0 + jc * 16 + c;
            int hh = nn >> 6, dd = nn & 63;
            ushort4 pkv;
            pkv.x = f2bf(acc[jc][0]); pkv.y = f2bf(acc[jc][1]);
            pkv.z = f2bf(acc[jc][2]); pkv.w = f2bf(acc[jc][3]);
            *(ushort4*)&vtd[(((long)(bb * 16 + hh) << 6) + dd) * 1024 + ii] = pkv;
        }
    } else {
        #pragma unroll
        for (int r = 0; r < 4; r++) {
            long mm = m0 + w * 16 + g * 4 + r;
            #pragma unroll
            for (int jc = 0; jc < 4; jc++) {
                int nn = n0 + jc * 16 + c;
                outf[mm * 1024 + nn] = acc[jc][r];
            }
        }
    }
}

// ---------------- K4: fused causal flash attention with fragment bias ---------
// grid 2048 = 64 i-tiles (heavy-first) x 32 (b,h); ONE wave per block, 16 rows.
// KVBLK=64, defer-rescale, fragment-layout bias (2 coalesced loads/tile).
__global__ __launch_bounds__(64) void k_attn(
    const unsigned short* __restrict__ Qs, const unsigned short* __restrict__ Ks,
    const unsigned short* __restrict__ VTs, const unsigned short* __restrict__ biasg,
    unsigned short* __restrict__ Os) {
    __shared__ unsigned short p_lds[16][72];
    int bid = blockIdx.x;
    int it = 63 - (bid >> 5);          // heavy stripes dispatched first
    int bh = bid & 31;
    int b = bh >> 4, h = bh & 15;
    int lane = threadIdx.x & 63;
    int g = lane >> 4, c = lane & 15;
    int i0 = it * 16;

    long plane = ((long)bh) << 16;                         // 1024*64 per head
    const unsigned short* Qp = Qs + plane;
    const unsigned short* Kp = Ks + plane;
    const unsigned short* Vp = VTs + plane;                // [64 d][1024 j]
    const unsigned short* Bt = biasg + (((long)bh * 64 + it) << 14); // *16*1024

    short8 q0 = *(const short8*)(Qp + (long)(i0 + c) * 64 + g * 8);
    short8 q1 = *(const short8*)(Qp + (long)(i0 + c) * 64 + 32 + g * 8);

    f32x4 zero = {0.f, 0.f, 0.f, 0.f};
    f32x4 o[4]; o[0] = zero; o[1] = zero; o[2] = zero; o[3] = zero;
    float m[4], l[4];
    #pragma unroll
    for (int r = 0; r < 4; r++) { m[r] = -1e30f; l[r] = 0.f; }

    int nj = (it >> 2) + 1;            // 64-col tiles
    for (int jt = 0; jt < nj; jt++) {
        int j0 = jt * 64;
        // ---- QK^T over 64 keys ----
        f32x4 s[4]; s[0] = zero; s[1] = zero; s[2] = zero; s[3] = zero;
        #pragma unroll
        for (int jj = 0; jj < 4; jj++) {
            const unsigned short* kr = Kp + (long)(j0 + jj * 16 + c) * 64 + g * 8;
            short8 ka = *(const short8*)(kr);
            short8 kb = *(const short8*)(kr + 32);
            s[jj] = __builtin_amdgcn_mfma_f32_16x16x32_bf16(q0, ka, s[jj], 0, 0, 0);
            s[jj] = __builtin_amdgcn_mfma_f32_16x16x32_bf16(q1, kb, s[jj], 0, 0, 0);
        }
        // ---- bias (fragment layout: 32B/lane contiguous) ----
        const unsigned short* bp = Bt + (jt << 10) + lane * 16;
        short8 bv0 = *(const short8*)(bp);
        short8 bv1 = *(const short8*)(bp + 8);
        #pragma unroll
        for (int r = 0; r < 4; r++) {
            #pragma unroll
            for (int jj = 0; jj < 4; jj++) {
                int idx = r * 4 + jj;
                float bb = (idx < 8) ? bf2f((unsigned short)bv0[idx])
                                     : bf2f((unsigned short)bv1[idx - 8]);
                s[jj][r] += bb;
            }
        }
        // ---- causal mask: only the last tile can be partial ----
        if (jt == nj - 1) {
            #pragma unroll
            for (int r = 0; r < 4; r++) {
                int i = i0 + g * 4 + r;
                #pragma unroll
                for (int jj = 0; jj < 4; jj++) {
                    if (j0 + jj * 16 + c > i) s[jj][r] = -1e30f;
                }
            }
        }
        // ---- online softmax with deferred rescale ----
        float pmax[4]; int need = 0;
        #pragma unroll
        for (int r = 0; r < 4; r++) {
            float mx = fmaxf(fmaxf(s[0][r], s[1][r]), fmaxf(s[2][r], s[3][r]));
            mx = fmaxf(mx, __shfl_xor(mx, 1));
            mx = fmaxf(mx, __shfl_xor(mx, 2));
            mx = fmaxf(mx, __shfl_xor(mx, 4));
            mx = fmaxf(mx, __shfl_xor(mx, 8));
            pmax[r] = mx;
            need |= (mx > m[r] + 8.0f) ? 1 : 0;
        }
        float pv[4][4];
        if (__any(need)) {
            #pragma unroll
            for (int r = 0; r < 4; r++) {
                float mn = fmaxf(m[r], pmax[r]);
                float al = exp2f((m[r] - mn) * LOG2E);
                float rs = 0.f;
                #pragma unroll
                for (int jj = 0; jj < 4; jj++) {
                    pv[jj][r] = exp2f((s[jj][r] - mn) * LOG2E);
                    rs += pv[jj][r];
                }
                rs += __shfl_xor(rs, 1); rs += __shfl_xor(rs, 2);
                rs += __shfl_xor(rs, 4); rs += __shfl_xor(rs, 8);
                l[r] = l[r] * al + rs;
                m[r] = mn;
                o[0][r] *= al; o[1][r] *= al; o[2][r] *= al; o[3][r] *= al;
            }
        } else {
            #pragma unroll
            for (int r = 0; r < 4; r++) {
                float rs = 0.f;
                #pragma unroll
                for (int jj = 0; jj < 4; jj++) {
                    pv[jj][r] = exp2f((s[jj][r] - m[r]) * LOG2E);
                    rs += pv[jj][r];
                }
                rs += __shfl_xor(rs, 1); rs += __shfl_xor(rs, 2);
                rs += __shfl_xor(rs, 4); rs += __shfl_xor(rs, 8);
                l[r] += rs;
            }
        }
        // ---- P -> LDS (transpose to A-fragment order) ----
        #pragma unroll
        for (int r = 0; r < 4; r++) {
            #pragma unroll
            for (int jj = 0; jj < 4; jj++) {
                p_lds[g * 4 + r][c + 16 * jj] = f2bf(pv[jj][r]);
            }
        }
        short8 pa0 = *(const short8*)&p_lds[c][g * 8];
        short8 pa1 = *(const short8*)&p_lds[c][32 + g * 8];
        // ---- PV ----
        #pragma unroll
        for (int dd = 0; dd < 4; dd++) {
            const unsigned short* vb = Vp + (long)(dd * 16 + c) * 1024 + j0 + g * 8;
            short8 v0 = *(const short8*)(vb);
            short8 v1 = *(const short8*)(vb + 32);
            o[dd] = __builtin_amdgcn_mfma_f32_16x16x32_bf16(pa0, v0, o[dd], 0, 0, 0);
            o[dd] = __builtin_amdgcn_mfma_f32_16x16x32_bf16(pa1, v1, o[dd], 0, 0, 0);
        }
    }
    #pragma unroll
    for (int r = 0; r < 4; r++) {
        float inv = 1.0f / l[r];
        int i = i0 + g * 4 + r;
        unsigned short* op = Os + ((long)(b * 1024 + i)) * 1024 + h * 64;
        #pragma unroll
        for (int dd = 0; dd < 4; dd++) op[dd * 16 + c] = f2bf(o[dd][r] * inv);
    }
}

// ------------------------------- launch ---------------------------------------
extern "C" void kernel_launch(void* const* d_in, const int* in_sizes, int n_in,
                              void* d_out, int out_size, void* d_ws, size_t ws_size,
                              hipStream_t stream) {
    const float* x     = (const float*)d_in[0];
    const float* Wq    = (const float*)d_in[1];
    const float* Wk    = (const float*)d_in[2];
    const float* Wv    = (const float*)d_in[3];
    const float* Wo    = (const float*)d_in[4];
    const float* Eidx  = (const float*)d_in[5];
    const float* Ebar  = (const float*)d_in[6];
    const float* Epos  = (const float*)d_in[7];
    const float* Eoct  = (const float*)d_in[8];
    const float* Esemi = (const float*)d_in[9];
    const int* barm    = (const int*)d_in[10];
    const int* posm    = (const int*)d_in[11];
    const int* octm    = (const int*)d_in[12];
    const int* semim   = (const int*)d_in[13];
    float* outf = (float*)d_out;

    unsigned short* w = (unsigned short*)d_ws;
    unsigned short* XB   = w;                   // 2M el
    unsigned short* WQB  = w + 2097152;         // 1M el each
    unsigned short* WKB  = w + 3145728;
    unsigned short* WVB  = w + 4194304;
    unsigned short* WOB  = w + 5242880;
    unsigned short* QS   = w + 6291456;         // (b,h,n,d)
    unsigned short* KS   = w + 8388608;
    unsigned short* VTS  = w + 10485760;        // (b,h,d,n)
    unsigned short* OS   = w + 12582912;        // (b,n,h*d)
    unsigned short* BIAS = w + 14680064;        // 32M el, fragment tiles

    k_convert<<<6144, 256, 0, stream>>>(x, Wq, Wk, Wv, Wo, w);
    k_bias<<<2048, 256, 0, stream>>>(Eidx, Ebar, Epos, Eoct, Esemi,
                                     barm, posm, octm, semim, BIAS);
    k_gemm<<<dim3(32, 16, 3), 256, 0, stream>>>(XB, WQB, WKB, WVB,
                                                QS, KS, VTS, nullptr, -1);
    k_attn<<<2048, 64, 0, stream>>>(QS, KS, VTS, BIAS, OS);
    k_gemm<<<dim3(32, 16, 1), 256, 0, stream>>>(OS, WOB, WOB, WOB,
                                                QS, KS, VTS, outf, 3);
}

// Round 5
// 131.736 us; speedup vs baseline: 1.5040x; 1.5040x over previous
//
#include <hip/hip_runtime.h>
#include <cstdint>

typedef __attribute__((ext_vector_type(8))) short short8;
typedef __attribute__((ext_vector_type(4))) float f32x4;

#define LOG2E 1.44269504088896340736f

static __device__ __forceinline__ float bf2f(unsigned short u) {
    union { unsigned int i; float f; } v; v.i = ((unsigned int)u) << 16; return v.f;
}
static __device__ __forceinline__ unsigned short f2bf(float f) {
    union { float f; unsigned int i; } v; v.f = f;
    unsigned int r = v.i + 0x7FFF + ((v.i >> 16) & 1);
    return (unsigned short)(r >> 16);
}

// ---------------- K1: fp32 -> bf16 convert (x, Wq, Wk, Wv, Wo) ----------------
__global__ __launch_bounds__(256) void k_convert(
    const float* __restrict__ x, const float* __restrict__ wq,
    const float* __restrict__ wk, const float* __restrict__ wv,
    const float* __restrict__ wo, unsigned short* __restrict__ dst) {
    long t = (long)blockIdx.x * 256 + threadIdx.x;
    long base = t * 4;
    const long NX = 2097152, NW = 1048576;
    const float* src; long off;
    if (base < NX)            { src = x;  off = base; }
    else if (base < NX + NW)  { src = wq; off = base - NX; }
    else if (base < NX + 2*NW){ src = wk; off = base - NX - NW; }
    else if (base < NX + 3*NW){ src = wv; off = base - NX - 2*NW; }
    else                      { src = wo; off = base - NX - 3*NW; }
    float4 v = *(const float4*)(src + off);
    ushort4 o;
    o.x = f2bf(v.x); o.y = f2bf(v.y); o.z = f2bf(v.z); o.w = f2bf(v.w);
    *(ushort4*)(dst + base) = o;
}

// ---------------- K2: bias materialization, transposed-table gathers ----------
// Tile (b,h,ti,tj): rows i0=ti*16..+15, cols j0=tj*64..+63.
// Output: MFMA-fragment tile layout; tile base = ((bh*64+ti)*16+tj)*1024;
// value (row, col) at position ((row>>2)*16 + (col&15))*16 + (row&3)*4 + (col>>4).
// LDS tables TRANSPOSED: lds_t[h*233 + s], s: [0,80)=Eidx slice, [80,97)=Ebar,
// [97,193)=Epos, [193,218)=Eoct, [218,231)=Esemi. Gather banks = (9h + s) % 32
// -> ~random 16-of-32 per 16-lane h-group (vs 2-of-32 in round 4).
__global__ __launch_bounds__(256) void k_bias(
    const float* __restrict__ Eidx, const float* __restrict__ Ebar,
    const float* __restrict__ Epos, const float* __restrict__ Eoct,
    const float* __restrict__ Esemi,
    const int* __restrict__ barm, const int* __restrict__ posm,
    const int* __restrict__ octm, const int* __restrict__ semim,
    unsigned short* __restrict__ biasg) {
    int bid = blockIdx.x;
    int tj = bid & 15, ti = (bid >> 4) & 63, b = bid >> 10;
    int i0 = ti * 16, j0 = tj * 64;
    if (j0 > i0 + 15) return;   // strictly-causal-masked tile: never read

    __shared__ float lds_t[16 * 233];    // transposed tables, 14.9 KB
    __shared__ int   pk[16 * 65];        // packed indices, pad 65

    int t = threadIdx.x;
    int rel_lo = i0 - j0 - 63; if (rel_lo < 0) rel_lo = 0;

    // stage transposed tables: idx = s*16 + h
    for (int idx = t; idx < 231 * 16; idx += 256) {
        int s = idx >> 4, h = idx & 15;
        float v;
        if (s < 80) {
            int src = rel_lo + s; if (src > 1023) src = 1023;
            v = Eidx[src * 16 + h];
        } else if (s < 97)  v = Ebar[(s - 80) * 16 + h];
        else if (s < 193)   v = Epos[(s - 97) * 16 + h];
        else if (s < 218)   v = Eoct[(s - 193) * 16 + h];
        else                v = Esemi[(s - 218) * 16 + h];
        lds_t[h * 233 + s] = v;
    }
    // stage packed indices (coalesced int reads)
    #pragma unroll
    for (int cc = 0; cc < 4; cc++) {
        int cell = t + cc * 256;
        int i = i0 + (cell >> 6), j = j0 + (cell & 63);
        long ij = ((long)b << 20) + ((long)i << 10) + j;
        int v = (barm[ij] + 1) | ((posm[ij] + 1) << 5) |
                ((octm[ij] + 1) << 12) | ((semim[ij] + 1) << 17);
        pk[(cell >> 6) * 65 + (cell & 63)] = v;
    }
    __syncthreads();

    int h = t >> 4, r = t & 15;
    int i = i0 + r;
    int base_rel = i - j0 - rel_lo;
    const float* T = &lds_t[h * 233];
    unsigned short* dst = biasg +
        ((((long)(b * 16 + h) * 64 + ti) * 16 + tj) << 10) + (r >> 2) * 256 + (r & 3) * 4;
    #pragma unroll 4
    for (int a = 0; a < 16; a++) {
        ushort4 ov;
        #pragma unroll
        for (int jj = 0; jj < 4; jj++) {
            int col = a + 16 * jj;
            int p = pk[r * 65 + col];
            int sr = base_rel - col; if (sr < 0) sr = 0;
            float v = T[sr]
                    + T[80  + (p & 31)]
                    + T[97  + ((p >> 5)  & 127)]
                    + T[193 + ((p >> 12) & 31)]
                    + T[218 + ((p >> 17) & 15)];
            ((unsigned short*)&ov)[jj] = f2bf(v * 0.125f);
        }
        *(ushort4*)(dst + a * 16) = ov;
    }
}

// ---------------- K3/K5: bf16 GEMM  C[M][N] = A[M][1024] * B[N][1024]^T -------
__global__ __launch_bounds__(256) void k_gemm(
    const unsigned short* __restrict__ A,
    const unsigned short* __restrict__ B0, const unsigned short* __restrict__ B1,
    const unsigned short* __restrict__ B2,
    unsigned short* __restrict__ qd, unsigned short* __restrict__ kd,
    unsigned short* __restrict__ vtd, float* __restrict__ outf, int mode) {
    __shared__ unsigned short As[64][72];
    __shared__ unsigned short Bs[64][72];
    int md = (mode < 0) ? (int)blockIdx.z : mode;
    const unsigned short* B = (md == 1) ? B1 : (md == 2) ? B2 : B0;
    int m0 = blockIdx.x * 64, n0 = blockIdx.y * 64;
    int t = threadIdx.x;
    int w = t >> 6, lane = t & 63, g = lane >> 4, c = lane & 15;
    int srow = t >> 2, scg = t & 3;
    const int K = 1024;
    f32x4 zero = {0.f, 0.f, 0.f, 0.f};
    f32x4 acc[4];
    acc[0] = zero; acc[1] = zero; acc[2] = zero; acc[3] = zero;

    for (int k0 = 0; k0 < K; k0 += 64) {
        __syncthreads();
        *(short8*)&As[srow][scg * 16]     = *(const short8*)(A + (long)(m0 + srow) * K + k0 + scg * 16);
        *(short8*)&As[srow][scg * 16 + 8] = *(const short8*)(A + (long)(m0 + srow) * K + k0 + scg * 16 + 8);
        *(short8*)&Bs[srow][scg * 16]     = *(const short8*)(B + (long)(n0 + srow) * K + k0 + scg * 16);
        *(short8*)&Bs[srow][scg * 16 + 8] = *(const short8*)(B + (long)(n0 + srow) * K + k0 + scg * 16 + 8);
        __syncthreads();
        #pragma unroll
        for (int kk = 0; kk < 2; kk++) {
            short8 a = *(const short8*)&As[w * 16 + c][kk * 32 + g * 8];
            #pragma unroll
            for (int jc = 0; jc < 4; jc++) {
                short8 bf = *(const short8*)&Bs[jc * 16 + c][kk * 32 + g * 8];
                acc[jc] = __builtin_amdgcn_mfma_f32_16x16x32_bf16(a, bf, acc[jc], 0, 0, 0);
            }
        }
    }

    if (md <= 1) {
        unsigned short* dst = (md == 0) ? qd : kd;
        float scale = (md == 0) ? 0.125f : 1.0f;
        #pragma unroll
        for (int r = 0; r < 4; r++) {
            int mm = m0 + w * 16 + g * 4 + r;
            int bb = mm >> 10, ii = mm & 1023;
            #pragma unroll
            for (int jc = 0; jc < 4; jc++) {
                int nn = n0 + jc * 16 + c;
                int hh = nn >> 6, dd = nn & 63;
                dst[(((long)(bb * 16 + hh) << 10) + ii) * 64 + dd] = f2bf(acc[jc][r] * scale);
            }
        }
    } else if (md == 2) {
        int mm0 = m0 + w * 16 + g * 4;
        int bb = mm0 >> 10, ii = mm0 & 1023;
        #pragma unroll
        for (int jc = 0; jc < 4; jc++) {
            int nn = n0 + jc * 16 + c;
            int hh = nn >> 6, dd = nn & 63;
            ushort4 pkv;
            pkv.x = f2bf(acc[jc][0]); pkv.y = f2bf(acc[jc][1]);
            pkv.z = f2bf(acc[jc][2]); pkv.w = f2bf(acc[jc][3]);
            *(ushort4*)&vtd[(((long)(bb * 16 + hh) << 6) + dd) * 1024 + ii] = pkv;
        }
    } else {
        #pragma unroll
        for (int r = 0; r < 4; r++) {
            long mm = m0 + w * 16 + g * 4 + r;
            #pragma unroll
            for (int jc = 0; jc < 4; jc++) {
                int nn = n0 + jc * 16 + c;
                outf[mm * 1024 + nn] = acc[jc][r];
            }
        }
    }
}

// ---------------- K4: fused causal flash attention with fragment bias ---------
// grid 2048 = 64 i-tiles (heavy-first) x 32 (b,h); ONE wave per block, 16 rows.
// KVBLK=64, defer-rescale, fragment-layout bias (2 coalesced loads/tile).
__global__ __launch_bounds__(64) void k_attn(
    const unsigned short* __restrict__ Qs, const unsigned short* __restrict__ Ks,
    const unsigned short* __restrict__ VTs, const unsigned short* __restrict__ biasg,
    unsigned short* __restrict__ Os) {
    __shared__ unsigned short p_lds[16][72];
    int bid = blockIdx.x;
    int it = 63 - (bid >> 5);          // heavy stripes dispatched first
    int bh = bid & 31;
    int b = bh >> 4, h = bh & 15;
    int lane = threadIdx.x & 63;
    int g = lane >> 4, c = lane & 15;
    int i0 = it * 16;

    long plane = ((long)bh) << 16;                         // 1024*64 per head
    const unsigned short* Qp = Qs + plane;
    const unsigned short* Kp = Ks + plane;
    const unsigned short* Vp = VTs + plane;                // [64 d][1024 j]
    const unsigned short* Bt = biasg + (((long)bh * 64 + it) << 14); // *16*1024

    short8 q0 = *(const short8*)(Qp + (long)(i0 + c) * 64 + g * 8);
    short8 q1 = *(const short8*)(Qp + (long)(i0 + c) * 64 + 32 + g * 8);

    f32x4 zero = {0.f, 0.f, 0.f, 0.f};
    f32x4 o[4]; o[0] = zero; o[1] = zero; o[2] = zero; o[3] = zero;
    float m[4], l[4];
    #pragma unroll
    for (int r = 0; r < 4; r++) { m[r] = -1e30f; l[r] = 0.f; }

    int nj = (it >> 2) + 1;            // 64-col tiles
    for (int jt = 0; jt < nj; jt++) {
        int j0 = jt * 64;
        // ---- QK^T over 64 keys ----
        f32x4 s[4]; s[0] = zero; s[1] = zero; s[2] = zero; s[3] = zero;
        #pragma unroll
        for (int jj = 0; jj < 4; jj++) {
            const unsigned short* kr = Kp + (long)(j0 + jj * 16 + c) * 64 + g * 8;
            short8 ka = *(const short8*)(kr);
            short8 kb = *(const short8*)(kr + 32);
            s[jj] = __builtin_amdgcn_mfma_f32_16x16x32_bf16(q0, ka, s[jj], 0, 0, 0);
            s[jj] = __builtin_amdgcn_mfma_f32_16x16x32_bf16(q1, kb, s[jj], 0, 0, 0);
        }
        // ---- bias (fragment layout: 32B/lane contiguous) ----
        const unsigned short* bp = Bt + (jt << 10) + lane * 16;
        short8 bv0 = *(const short8*)(bp);
        short8 bv1 = *(const short8*)(bp + 8);
        #pragma unroll
        for (int r = 0; r < 4; r++) {
            #pragma unroll
            for (int jj = 0; jj < 4; jj++) {
                int idx = r * 4 + jj;
                float bb = (idx < 8) ? bf2f((unsigned short)bv0[idx])
                                     : bf2f((unsigned short)bv1[idx - 8]);
                s[jj][r] += bb;
            }
        }
        // ---- causal mask: only the last tile can be partial ----
        if (jt == nj - 1) {
            #pragma unroll
            for (int r = 0; r < 4; r++) {
                int i = i0 + g * 4 + r;
                #pragma unroll
                for (int jj = 0; jj < 4; jj++) {
                    if (j0 + jj * 16 + c > i) s[jj][r] = -1e30f;
                }
            }
        }
        // ---- online softmax with deferred rescale ----
        float pmax[4]; int need = 0;
        #pragma unroll
        for (int r = 0; r < 4; r++) {
            float mx = fmaxf(fmaxf(s[0][r], s[1][r]), fmaxf(s[2][r], s[3][r]));
            mx = fmaxf(mx, __shfl_xor(mx, 1));
            mx = fmaxf(mx, __shfl_xor(mx, 2));
            mx = fmaxf(mx, __shfl_xor(mx, 4));
            mx = fmaxf(mx, __shfl_xor(mx, 8));
            pmax[r] = mx;
            need |= (mx > m[r] + 8.0f) ? 1 : 0;
        }
        float pv[4][4];
        if (__any(need)) {
            #pragma unroll
            for (int r = 0; r < 4; r++) {
                float mn = fmaxf(m[r], pmax[r]);
                float al = exp2f((m[r] - mn) * LOG2E);
                float rs = 0.f;
                #pragma unroll
                for (int jj = 0; jj < 4; jj++) {
                    pv[jj][r] = exp2f((s[jj][r] - mn) * LOG2E);
                    rs += pv[jj][r];
                }
                rs += __shfl_xor(rs, 1); rs += __shfl_xor(rs, 2);
                rs += __shfl_xor(rs, 4); rs += __shfl_xor(rs, 8);
                l[r] = l[r] * al + rs;
                m[r] = mn;
                o[0][r] *= al; o[1][r] *= al; o[2][r] *= al; o[3][r] *= al;
            }
        } else {
            #pragma unroll
            for (int r = 0; r < 4; r++) {
                float rs = 0.f;
                #pragma unroll
                for (int jj = 0; jj < 4; jj++) {
                    pv[jj][r] = exp2f((s[jj][r] - m[r]) * LOG2E);
                    rs += pv[jj][r];
                }
                rs += __shfl_xor(rs, 1); rs += __shfl_xor(rs, 2);
                rs += __shfl_xor(rs, 4); rs += __shfl_xor(rs, 8);
                l[r] += rs;
            }
        }
        // ---- P -> LDS (transpose to A-fragment order) ----
        #pragma unroll
        for (int r = 0; r < 4; r++) {
            #pragma unroll
            for (int jj = 0; jj < 4; jj++) {
                p_lds[g * 4 + r][c + 16 * jj] = f2bf(pv[jj][r]);
            }
        }
        short8 pa0 = *(const short8*)&p_lds[c][g * 8];
        short8 pa1 = *(const short8*)&p_lds[c][32 + g * 8];
        // ---- PV ----
        #pragma unroll
        for (int dd = 0; dd < 4; dd++) {
            const unsigned short* vb = Vp + (long)(dd * 16 + c) * 1024 + j0 + g * 8;
            short8 v0 = *(const short8*)(vb);
            short8 v1 = *(const short8*)(vb + 32);
            o[dd] = __builtin_amdgcn_mfma_f32_16x16x32_bf16(pa0, v0, o[dd], 0, 0, 0);
            o[dd] = __builtin_amdgcn_mfma_f32_16x16x32_bf16(pa1, v1, o[dd], 0, 0, 0);
        }
    }
    #pragma unroll
    for (int r = 0; r < 4; r++) {
        float inv = 1.0f / l[r];
        int i = i0 + g * 4 + r;
        unsigned short* op = Os + ((long)(b * 1024 + i)) * 1024 + h * 64;
        #pragma unroll
        for (int dd = 0; dd < 4; dd++) op[dd * 16 + c] = f2bf(o[dd][r] * inv);
    }
}

// ------------------------------- launch ---------------------------------------
extern "C" void kernel_launch(void* const* d_in, const int* in_sizes, int n_in,
                              void* d_out, int out_size, void* d_ws, size_t ws_size,
                              hipStream_t stream) {
    const float* x     = (const float*)d_in[0];
    const float* Wq    = (const float*)d_in[1];
    const float* Wk    = (const float*)d_in[2];
    const float* Wv    = (const float*)d_in[3];
    const float* Wo    = (const float*)d_in[4];
    const float* Eidx  = (const float*)d_in[5];
    const float* Ebar  = (const float*)d_in[6];
    const float* Epos  = (const float*)d_in[7];
    const float* Eoct  = (const float*)d_in[8];
    const float* Esemi = (const float*)d_in[9];
    const int* barm    = (const int*)d_in[10];
    const int* posm    = (const int*)d_in[11];
    const int* octm    = (const int*)d_in[12];
    const int* semim   = (const int*)d_in[13];
    float* outf = (float*)d_out;

    unsigned short* w = (unsigned short*)d_ws;
    unsigned short* XB   = w;                   // 2M el
    unsigned short* WQB  = w + 2097152;         // 1M el each
    unsigned short* WKB  = w + 3145728;
    unsigned short* WVB  = w + 4194304;
    unsigned short* WOB  = w + 5242880;
    unsigned short* QS   = w + 6291456;         // (b,h,n,d)
    unsigned short* KS   = w + 8388608;
    unsigned short* VTS  = w + 10485760;        // (b,h,d,n)
    unsigned short* OS   = w + 12582912;        // (b,n,h*d)
    unsigned short* BIAS = w + 14680064;        // 32M el, fragment tiles

    k_convert<<<6144, 256, 0, stream>>>(x, Wq, Wk, Wv, Wo, w);
    k_bias<<<2048, 256, 0, stream>>>(Eidx, Ebar, Epos, Eoct, Esemi,
                                     barm, posm, octm, semim, BIAS);
    k_gemm<<<dim3(32, 16, 3), 256, 0, stream>>>(XB, WQB, WKB, WVB,
                                                QS, KS, VTS, nullptr, -1);
    k_attn<<<2048, 64, 0, stream>>>(QS, KS, VTS, BIAS, OS);
    k_gemm<<<dim3(32, 16, 1), 256, 0, stream>>>(OS, WOB, WOB, WOB,
                                                QS, KS, VTS, outf, 3);
}

// Round 6
// 123.947 us; speedup vs baseline: 1.5986x; 1.0628x over previous
//
#include <hip/hip_runtime.h>
#include <cstdint>

typedef __attribute__((ext_vector_type(8))) short short8;
typedef __attribute__((ext_vector_type(4))) float f32x4;

#define LOG2E 1.44269504088896340736f

static __device__ __forceinline__ float bf2f(unsigned short u) {
    union { unsigned int i; float f; } v; v.i = ((unsigned int)u) << 16; return v.f;
}
static __device__ __forceinline__ unsigned short f2bf(float f) {
    union { float f; unsigned int i; } v; v.f = f;
    unsigned int r = v.i + 0x7FFF + ((v.i >> 16) & 1);
    return (unsigned short)(r >> 16);
}

// ---------------- K1: fp32 -> bf16 convert (x, Wq, Wk, Wv, Wo) ----------------
__global__ __launch_bounds__(256) void k_convert(
    const float* __restrict__ x, const float* __restrict__ wq,
    const float* __restrict__ wk, const float* __restrict__ wv,
    const float* __restrict__ wo, unsigned short* __restrict__ dst) {
    long t = (long)blockIdx.x * 256 + threadIdx.x;
    long base = t * 4;
    const long NX = 2097152, NW = 1048576;
    const float* src; long off;
    if (base < NX)            { src = x;  off = base; }
    else if (base < NX + NW)  { src = wq; off = base - NX; }
    else if (base < NX + 2*NW){ src = wk; off = base - NX - NW; }
    else if (base < NX + 3*NW){ src = wv; off = base - NX - 2*NW; }
    else                      { src = wo; off = base - NX - 3*NW; }
    float4 v = *(const float4*)(src + off);
    ushort4 o;
    o.x = f2bf(v.x); o.y = f2bf(v.y); o.z = f2bf(v.z); o.w = f2bf(v.w);
    *(ushort4*)(dst + base) = o;
}

// ---------------- K2: bias materialization, transposed-table gathers ----------
// (unchanged from round 5 — validated: left top-5, conflicts fixed)
__global__ __launch_bounds__(256) void k_bias(
    const float* __restrict__ Eidx, const float* __restrict__ Ebar,
    const float* __restrict__ Epos, const float* __restrict__ Eoct,
    const float* __restrict__ Esemi,
    const int* __restrict__ barm, const int* __restrict__ posm,
    const int* __restrict__ octm, const int* __restrict__ semim,
    unsigned short* __restrict__ biasg) {
    int bid = blockIdx.x;
    int tj = bid & 15, ti = (bid >> 4) & 63, b = bid >> 10;
    int i0 = ti * 16, j0 = tj * 64;
    if (j0 > i0 + 15) return;   // strictly-causal-masked tile: never read

    __shared__ float lds_t[16 * 233];    // transposed tables, 14.9 KB
    __shared__ int   pk[16 * 65];        // packed indices, pad 65

    int t = threadIdx.x;
    int rel_lo = i0 - j0 - 63; if (rel_lo < 0) rel_lo = 0;

    for (int idx = t; idx < 231 * 16; idx += 256) {
        int s = idx >> 4, h = idx & 15;
        float v;
        if (s < 80) {
            int src = rel_lo + s; if (src > 1023) src = 1023;
            v = Eidx[src * 16 + h];
        } else if (s < 97)  v = Ebar[(s - 80) * 16 + h];
        else if (s < 193)   v = Epos[(s - 97) * 16 + h];
        else if (s < 218)   v = Eoct[(s - 193) * 16 + h];
        else                v = Esemi[(s - 218) * 16 + h];
        lds_t[h * 233 + s] = v;
    }
    #pragma unroll
    for (int cc = 0; cc < 4; cc++) {
        int cell = t + cc * 256;
        int i = i0 + (cell >> 6), j = j0 + (cell & 63);
        long ij = ((long)b << 20) + ((long)i << 10) + j;
        int v = (barm[ij] + 1) | ((posm[ij] + 1) << 5) |
                ((octm[ij] + 1) << 12) | ((semim[ij] + 1) << 17);
        pk[(cell >> 6) * 65 + (cell & 63)] = v;
    }
    __syncthreads();

    int h = t >> 4, r = t & 15;
    int i = i0 + r;
    int base_rel = i - j0 - rel_lo;
    const float* T = &lds_t[h * 233];
    unsigned short* dst = biasg +
        ((((long)(b * 16 + h) * 64 + ti) * 16 + tj) << 10) + (r >> 2) * 256 + (r & 3) * 4;
    #pragma unroll 4
    for (int a = 0; a < 16; a++) {
        ushort4 ov;
        #pragma unroll
        for (int jj = 0; jj < 4; jj++) {
            int col = a + 16 * jj;
            int p = pk[r * 65 + col];
            int sr = base_rel - col; if (sr < 0) sr = 0;
            float v = T[sr]
                    + T[80  + (p & 31)]
                    + T[97  + ((p >> 5)  & 127)]
                    + T[193 + ((p >> 12) & 31)]
                    + T[218 + ((p >> 17) & 15)];
            ((unsigned short*)&ov)[jj] = f2bf(v * 0.125f);
        }
        *(ushort4*)(dst + a * 16) = ov;
    }
}

// ---------------- K3/K5: bf16 GEMM  C[M][N] = A[M][1024] * B[N][1024]^T -------
__global__ __launch_bounds__(256) void k_gemm(
    const unsigned short* __restrict__ A,
    const unsigned short* __restrict__ B0, const unsigned short* __restrict__ B1,
    const unsigned short* __restrict__ B2,
    unsigned short* __restrict__ qd, unsigned short* __restrict__ kd,
    unsigned short* __restrict__ vtd, float* __restrict__ outf, int mode) {
    __shared__ unsigned short As[64][72];
    __shared__ unsigned short Bs[64][72];
    int md = (mode < 0) ? (int)blockIdx.z : mode;
    const unsigned short* B = (md == 1) ? B1 : (md == 2) ? B2 : B0;
    int m0 = blockIdx.x * 64, n0 = blockIdx.y * 64;
    int t = threadIdx.x;
    int w = t >> 6, lane = t & 63, g = lane >> 4, c = lane & 15;
    int srow = t >> 2, scg = t & 3;
    const int K = 1024;
    f32x4 zero = {0.f, 0.f, 0.f, 0.f};
    f32x4 acc[4];
    acc[0] = zero; acc[1] = zero; acc[2] = zero; acc[3] = zero;

    for (int k0 = 0; k0 < K; k0 += 64) {
        __syncthreads();
        *(short8*)&As[srow][scg * 16]     = *(const short8*)(A + (long)(m0 + srow) * K + k0 + scg * 16);
        *(short8*)&As[srow][scg * 16 + 8] = *(const short8*)(A + (long)(m0 + srow) * K + k0 + scg * 16 + 8);
        *(short8*)&Bs[srow][scg * 16]     = *(const short8*)(B + (long)(n0 + srow) * K + k0 + scg * 16);
        *(short8*)&Bs[srow][scg * 16 + 8] = *(const short8*)(B + (long)(n0 + srow) * K + k0 + scg * 16 + 8);
        __syncthreads();
        #pragma unroll
        for (int kk = 0; kk < 2; kk++) {
            short8 a = *(const short8*)&As[w * 16 + c][kk * 32 + g * 8];
            #pragma unroll
            for (int jc = 0; jc < 4; jc++) {
                short8 bf = *(const short8*)&Bs[jc * 16 + c][kk * 32 + g * 8];
                acc[jc] = __builtin_amdgcn_mfma_f32_16x16x32_bf16(a, bf, acc[jc], 0, 0, 0);
            }
        }
    }

    if (md <= 1) {
        unsigned short* dst = (md == 0) ? qd : kd;
        float scale = (md == 0) ? 0.125f : 1.0f;
        #pragma unroll
        for (int r = 0; r < 4; r++) {
            int mm = m0 + w * 16 + g * 4 + r;
            int bb = mm >> 10, ii = mm & 1023;
            #pragma unroll
            for (int jc = 0; jc < 4; jc++) {
                int nn = n0 + jc * 16 + c;
                int hh = nn >> 6, dd = nn & 63;
                dst[(((long)(bb * 16 + hh) << 10) + ii) * 64 + dd] = f2bf(acc[jc][r] * scale);
            }
        }
    } else if (md == 2) {
        int mm0 = m0 + w * 16 + g * 4;
        int bb = mm0 >> 10, ii = mm0 & 1023;
        #pragma unroll
        for (int jc = 0; jc < 4; jc++) {
            int nn = n0 + jc * 16 + c;
            int hh = nn >> 6, dd = nn & 63;
            ushort4 pkv;
            pkv.x = f2bf(acc[jc][0]); pkv.y = f2bf(acc[jc][1]);
            pkv.z = f2bf(acc[jc][2]); pkv.w = f2bf(acc[jc][3]);
            *(ushort4*)&vtd[(((long)(bb * 16 + hh) << 6) + dd) * 1024 + ii] = pkv;
        }
    } else {
        #pragma unroll
        for (int r = 0; r < 4; r++) {
            long mm = m0 + w * 16 + g * 4 + r;
            #pragma unroll
            for (int jc = 0; jc < 4; jc++) {
                int nn = n0 + jc * 16 + c;
                outf[mm * 1024 + nn] = acc[jc][r];
            }
        }
    }
}

// ---------------- K4: flash attention, fixed-max softmax, 4-wave j-split ------
// grid 2048 = 64 i-tiles (heavy-first) x 32 (b,h); 4 waves split j-tiles
// round-robin; fixed softmax shift m=8 (scores |s|<~4) => no max reduce, no
// rescale, cross-wave combine is a plain LDS sum of (O, l).
__global__ __launch_bounds__(256) void k_attn(
    const unsigned short* __restrict__ Qs, const unsigned short* __restrict__ Ks,
    const unsigned short* __restrict__ VTs, const unsigned short* __restrict__ biasg,
    unsigned short* __restrict__ Os) {
    // per-wave 5632B: [0,2304) p_lds 16x72 u16 (loop) / reused [0,4352) oc 64x17 f32
    // + [4352,5632) lc 64x5 f32 (combine). Strides 17/5: bank-spread.
    __shared__ char smem[4 * 5632];
    int bid = blockIdx.x;
    int it = 63 - (bid >> 5);          // heavy stripes dispatched first
    int bh = bid & 31;
    int b = bh >> 4, h = bh & 15;
    int w = threadIdx.x >> 6;
    int lane = threadIdx.x & 63;
    int g = lane >> 4, c = lane & 15;
    int i0 = it * 16;

    char* wbase = smem + w * 5632;
    unsigned short* p_lds = (unsigned short*)wbase;        // [16][72]

    long plane = ((long)bh) << 16;                         // 1024*64 per head
    const unsigned short* Qp = Qs + plane;
    const unsigned short* Kp = Ks + plane;
    const unsigned short* Vp = VTs + plane;                // [64 d][1024 j]
    const unsigned short* Bt = biasg + (((long)bh * 64 + it) << 14);

    short8 q0 = *(const short8*)(Qp + (long)(i0 + c) * 64 + g * 8);
    short8 q1 = *(const short8*)(Qp + (long)(i0 + c) * 64 + 32 + g * 8);

    f32x4 zero = {0.f, 0.f, 0.f, 0.f};
    f32x4 o[4]; o[0] = zero; o[1] = zero; o[2] = zero; o[3] = zero;
    float l[4] = {0.f, 0.f, 0.f, 0.f};

    int nj = (it >> 2) + 1;            // 64-col tiles
    for (int jt = w; jt < nj; jt += 4) {
        int j0 = jt * 64;
        // ---- QK^T over 64 keys ----
        f32x4 s[4]; s[0] = zero; s[1] = zero; s[2] = zero; s[3] = zero;
        #pragma unroll
        for (int jj = 0; jj < 4; jj++) {
            const unsigned short* kr = Kp + (long)(j0 + jj * 16 + c) * 64 + g * 8;
            short8 ka = *(const short8*)(kr);
            short8 kb = *(const short8*)(kr + 32);
            s[jj] = __builtin_amdgcn_mfma_f32_16x16x32_bf16(q0, ka, s[jj], 0, 0, 0);
            s[jj] = __builtin_amdgcn_mfma_f32_16x16x32_bf16(q1, kb, s[jj], 0, 0, 0);
        }
        // ---- bias (fragment layout: 32B/lane contiguous) ----
        const unsigned short* bp = Bt + (jt << 10) + lane * 16;
        short8 bv0 = *(const short8*)(bp);
        short8 bv1 = *(const short8*)(bp + 8);
        #pragma unroll
        for (int r = 0; r < 4; r++) {
            #pragma unroll
            for (int jj = 0; jj < 4; jj++) {
                int idx = r * 4 + jj;
                float bb = (idx < 8) ? bf2f((unsigned short)bv0[idx])
                                     : bf2f((unsigned short)bv1[idx - 8]);
                s[jj][r] += bb;
            }
        }
        // ---- causal mask: only the last tile can be partial ----
        if (jt == nj - 1) {
            #pragma unroll
            for (int r = 0; r < 4; r++) {
                int i = i0 + g * 4 + r;
                #pragma unroll
                for (int jj = 0; jj < 4; jj++) {
                    if (j0 + jj * 16 + c > i) s[jj][r] = -1e9f;
                }
            }
        }
        // ---- fixed-shift softmax: p = exp2((s-8)*log2e); per-lane l partial --
        #pragma unroll
        for (int r = 0; r < 4; r++) {
            #pragma unroll
            for (int jj = 0; jj < 4; jj++) {
                float p = exp2f(__builtin_fmaf(s[jj][r], LOG2E, -8.0f * LOG2E));
                l[r] += p;
                union { float f; unsigned int u; } pu; pu.f = p;
                p_lds[(g * 4 + r) * 72 + c + 16 * jj] = (unsigned short)(pu.u >> 16);
            }
        }
        short8 pa0 = *(const short8*)&p_lds[c * 72 + g * 8];
        short8 pa1 = *(const short8*)&p_lds[c * 72 + 32 + g * 8];
        // ---- PV ----
        #pragma unroll
        for (int dd = 0; dd < 4; dd++) {
            const unsigned short* vb = Vp + (long)(dd * 16 + c) * 1024 + j0 + g * 8;
            short8 v0 = *(const short8*)(vb);
            short8 v1 = *(const short8*)(vb + 32);
            o[dd] = __builtin_amdgcn_mfma_f32_16x16x32_bf16(pa0, v0, o[dd], 0, 0, 0);
            o[dd] = __builtin_amdgcn_mfma_f32_16x16x32_bf16(pa1, v1, o[dd], 0, 0, 0);
        }
    }
    // ---- cross-wave combine: plain sums (no rescale; shared fixed shift) ----
    float* oc = (float*)wbase;                 // [64][17] (reuses p_lds space)
    float* lc = (float*)(wbase + 4352);        // [64][5]
    #pragma unroll
    for (int dd = 0; dd < 4; dd++)
        #pragma unroll
        for (int r = 0; r < 4; r++)
            oc[lane * 17 + dd * 4 + r] = o[dd][r];
    #pragma unroll
    for (int r = 0; r < 4; r++) lc[lane * 5 + r] = l[r];
    __syncthreads();

    if (w == 0) {
        float linv[4];
        #pragma unroll
        for (int r = 0; r < 4; r++) {
            float lv = 0.f;
            #pragma unroll
            for (int ww = 0; ww < 4; ww++)
                lv += ((const float*)(smem + ww * 5632 + 4352))[lane * 5 + r];
            lv += __shfl_xor(lv, 1); lv += __shfl_xor(lv, 2);
            lv += __shfl_xor(lv, 4); lv += __shfl_xor(lv, 8);
            linv[r] = 1.0f / lv;
        }
        #pragma unroll
        for (int r = 0; r < 4; r++) {
            int i = i0 + g * 4 + r;
            unsigned short* op = Os + ((long)(b * 1024 + i)) * 1024 + h * 64;
            #pragma unroll
            for (int dd = 0; dd < 4; dd++) {
                float ov = 0.f;
                #pragma unroll
                for (int ww = 0; ww < 4; ww++)
                    ov += ((const float*)(smem + ww * 5632))[lane * 17 + dd * 4 + r];
                op[dd * 16 + c] = f2bf(ov * linv[r]);
            }
        }
    }
}

// ------------------------------- launch ---------------------------------------
extern "C" void kernel_launch(void* const* d_in, const int* in_sizes, int n_in,
                              void* d_out, int out_size, void* d_ws, size_t ws_size,
                              hipStream_t stream) {
    const float* x     = (const float*)d_in[0];
    const float* Wq    = (const float*)d_in[1];
    const float* Wk    = (const float*)d_in[2];
    const float* Wv    = (const float*)d_in[3];
    const float* Wo    = (const float*)d_in[4];
    const float* Eidx  = (const float*)d_in[5];
    const float* Ebar  = (const float*)d_in[6];
    const float* Epos  = (const float*)d_in[7];
    const float* Eoct  = (const float*)d_in[8];
    const float* Esemi = (const float*)d_in[9];
    const int* barm    = (const int*)d_in[10];
    const int* posm    = (const int*)d_in[11];
    const int* octm    = (const int*)d_in[12];
    const int* semim   = (const int*)d_in[13];
    float* outf = (float*)d_out;

    unsigned short* w = (unsigned short*)d_ws;
    unsigned short* XB   = w;                   // 2M el
    unsigned short* WQB  = w + 2097152;         // 1M el each
    unsigned short* WKB  = w + 3145728;
    unsigned short* WVB  = w + 4194304;
    unsigned short* WOB  = w + 5242880;
    unsigned short* QS   = w + 6291456;         // (b,h,n,d)
    unsigned short* KS   = w + 8388608;
    unsigned short* VTS  = w + 10485760;        // (b,h,d,n)
    unsigned short* OS   = w + 12582912;        // (b,n,h*d)
    unsigned short* BIAS = w + 14680064;        // 32M el, fragment tiles

    k_convert<<<6144, 256, 0, stream>>>(x, Wq, Wk, Wv, Wo, w);
    k_bias<<<2048, 256, 0, stream>>>(Eidx, Ebar, Epos, Eoct, Esemi,
                                     barm, posm, octm, semim, BIAS);
    k_gemm<<<dim3(32, 16, 3), 256, 0, stream>>>(XB, WQB, WKB, WVB,
                                                QS, KS, VTS, nullptr, -1);
    k_attn<<<2048, 256, 0, stream>>>(QS, KS, VTS, BIAS, OS);
    k_gemm<<<dim3(32, 16, 1), 256, 0, stream>>>(OS, WOB, WOB, WOB,
                                                QS, KS, VTS, outf, 3);
}

// Round 9
// 119.931 us; speedup vs baseline: 1.6521x; 1.0335x over previous
//
#include <hip/hip_runtime.h>
#include <cstdint>
#include <math.h>

typedef __attribute__((ext_vector_type(8))) short short8;
typedef __attribute__((ext_vector_type(4))) float f32x4;

#define LOG2E 1.44269504088896340736f

static __device__ __forceinline__ float bf2f(unsigned short u) {
    union { unsigned int i; float f; } v; v.i = ((unsigned int)u) << 16; return v.f;
}
static __device__ __forceinline__ unsigned short f2bf(float f) {
    union { float f; unsigned int i; } v; v.f = f;
    unsigned int r = v.i + 0x7FFF + ((v.i >> 16) & 1);
    return (unsigned short)(r >> 16);
}

// ---------------- K1: fp32 -> bf16 convert (x, Wq, Wk, Wv, Wo) ----------------
__global__ __launch_bounds__(256) void k_convert(
    const float* __restrict__ x, const float* __restrict__ wq,
    const float* __restrict__ wk, const float* __restrict__ wv,
    const float* __restrict__ wo, unsigned short* __restrict__ dst) {
    long t = (long)blockIdx.x * 256 + threadIdx.x;
    long base = t * 4;
    const long NX = 2097152, NW = 1048576;
    const float* src; long off;
    if (base < NX)            { src = x;  off = base; }
    else if (base < NX + NW)  { src = wq; off = base - NX; }
    else if (base < NX + 2*NW){ src = wk; off = base - NX - NW; }
    else if (base < NX + 3*NW){ src = wv; off = base - NX - 2*NW; }
    else                      { src = wo; off = base - NX - 3*NW; }
    float4 v = *(const float4*)(src + off);
    ushort4 o;
    o.x = f2bf(v.x); o.y = f2bf(v.y); o.z = f2bf(v.z); o.w = f2bf(v.w);
    *(ushort4*)(dst + base) = o;
}

// ---------------- K2: bias materialization, compact grid + dual-h float2 ------
// grid = 1088 active lower-triangle tiles (544/b). Tables as float2 (h, h+8):
// half the LDS gathers per output. Output: MFMA-fragment tile layout
// (value (row,col) at ((row>>2)*16+(col&15))*16 + (row&3)*4 + (col>>4)).
__global__ __launch_bounds__(256) void k_bias(
    const float* __restrict__ Eidx, const float* __restrict__ Ebar,
    const float* __restrict__ Epos, const float* __restrict__ Eoct,
    const float* __restrict__ Esemi,
    const int* __restrict__ barm, const int* __restrict__ posm,
    const int* __restrict__ octm, const int* __restrict__ semim,
    unsigned short* __restrict__ biasg) {
    // decode flat id -> (b, ti, tj) over lower-triangle tiles
    int fid = blockIdx.x;
    int b = (fid >= 544) ? 1 : 0;
    int f = fid - b * 544;
    int ti, tj;
    if (f >= 480) { int rr = f - 480; ti = 60 + (rr >> 4); tj = rr & 15; }
    else {
        int g = (int)(0.5f * (sqrtf(1.0f + 2.0f * (float)f) - 1.0f));
        while (2 * (g + 1) * (g + 2) <= f) g++;
        while (2 * g * (g + 1) > f) g--;
        int rr = f - 2 * g * (g + 1);
        int q = rr / (g + 1);
        ti = g * 4 + q;
        tj = rr - q * (g + 1);
    }
    int i0 = ti * 16, j0 = tj * 64;

    __shared__ float2 t2[8 * 233];       // (h, h+8) pairs, 14.9 KB
    __shared__ int    pk[16 * 65];       // packed indices, pad 65

    int t = threadIdx.x;
    int rel_lo = i0 - j0 - 63; if (rel_lo < 0) rel_lo = 0;

    // stage tables: idx = s*8 + h2; s: [0,80)=Eidx, [80,97)=Ebar,
    // [97,193)=Epos, [193,218)=Eoct, [218,231)=Esemi
    for (int idx = t; idx < 231 * 8; idx += 256) {
        int s = idx >> 3, h2 = idx & 7;
        float va, vb;
        if (s < 80) {
            int src = rel_lo + s; if (src > 1023) src = 1023;
            va = Eidx[src * 16 + h2]; vb = Eidx[src * 16 + h2 + 8];
        } else if (s < 97)  { va = Ebar[(s - 80) * 16 + h2];  vb = Ebar[(s - 80) * 16 + h2 + 8]; }
        else if (s < 193)   { va = Epos[(s - 97) * 16 + h2];  vb = Epos[(s - 97) * 16 + h2 + 8]; }
        else if (s < 218)   { va = Eoct[(s - 193) * 16 + h2]; vb = Eoct[(s - 193) * 16 + h2 + 8]; }
        else                { va = Esemi[(s - 218) * 16 + h2]; vb = Esemi[(s - 218) * 16 + h2 + 8]; }
        t2[h2 * 233 + s] = make_float2(va, vb);
    }
    #pragma unroll
    for (int cc = 0; cc < 4; cc++) {
        int cell = t + cc * 256;
        int i = i0 + (cell >> 6), j = j0 + (cell & 63);
        long ij = ((long)b << 20) + ((long)i << 10) + j;
        int v = (barm[ij] + 1) | ((posm[ij] + 1) << 5) |
                ((octm[ij] + 1) << 12) | ((semim[ij] + 1) << 17);
        pk[(cell >> 6) * 65 + (cell & 63)] = v;
    }
    __syncthreads();

    int r = t & 15, h2 = (t >> 4) & 7, ah = t >> 7;    // a = ah*8 + aa
    int i = i0 + r;
    int base_rel = i - j0 - rel_lo;
    const float2* T = &t2[h2 * 233];
    long frag = (r >> 2) * 256 + (r & 3) * 4;
    unsigned short* dstL = biasg + ((((long)(b * 16 + h2)     * 64 + ti) * 16 + tj) << 10) + frag;
    unsigned short* dstH = biasg + ((((long)(b * 16 + h2 + 8) * 64 + ti) * 16 + tj) << 10) + frag;
    #pragma unroll 4
    for (int aa = 0; aa < 8; aa++) {
        int a = ah * 8 + aa;
        ushort4 ovL, ovH;
        #pragma unroll
        for (int jj = 0; jj < 4; jj++) {
            int col = a + 16 * jj;
            int p = pk[r * 65 + col];
            int sr = base_rel - col; if (sr < 0) sr = 0;
            float2 v0 = T[sr];
            float2 v1 = T[80  + (p & 31)];
            float2 v2 = T[97  + ((p >> 5)  & 127)];
            float2 v3 = T[193 + ((p >> 12) & 31)];
            float2 v4 = T[218 + ((p >> 17) & 15)];
            float xL = v0.x + v1.x + v2.x + v3.x + v4.x;
            float xH = v0.y + v1.y + v2.y + v3.y + v4.y;
            ((unsigned short*)&ovL)[jj] = f2bf(xL * 0.125f);
            ((unsigned short*)&ovH)[jj] = f2bf(xH * 0.125f);
        }
        *(ushort4*)(dstL + a * 16) = ovL;
        *(ushort4*)(dstH + a * 16) = ovH;
    }
}

// ---------------- K3/K5: bf16 GEMM, 128x128 tile, global_load_lds (m97) -------
// C[M][N] = A[M][1024] * B[N][1024]^T. mode<0: z in {0:Q(1/8),1:K,2:V^T}; 3: f32.
__global__ __launch_bounds__(256) void k_gemm(
    const unsigned short* __restrict__ A,
    const unsigned short* __restrict__ B0, const unsigned short* __restrict__ B1,
    const unsigned short* __restrict__ B2,
    unsigned short* __restrict__ qd, unsigned short* __restrict__ kd,
    unsigned short* __restrict__ vtd, float* __restrict__ outf, int mode) {
    __shared__ unsigned short As[128 * 64];   // 16 KB, linear (gload_lds dest)
    __shared__ unsigned short Bs[128 * 64];
    int md = (mode < 0) ? (int)blockIdx.z : mode;
    const unsigned short* B = (md == 1) ? B1 : (md == 2) ? B2 : B0;
    int m0 = blockIdx.x * 128, n0 = blockIdx.y * 128;
    int t = threadIdx.x;
    int w = t >> 6, lane = t & 63, g = lane >> 4, c = lane & 15;
    int wr = w >> 1, wc = w & 1;
    const int K = 1024;
    f32x4 zero = {0.f, 0.f, 0.f, 0.f};
    f32x4 acc[4][4];
    #pragma unroll
    for (int m = 0; m < 4; m++)
        #pragma unroll
        for (int n = 0; n < 4; n++) acc[m][n] = zero;

    int srow = w * 8 + (lane >> 3);      // + q*32
    int scol = (lane & 7) * 8;           // element offset within BK
    for (int k0 = 0; k0 < K; k0 += 64) {
        __syncthreads();
        #pragma unroll
        for (int q = 0; q < 4; q++) {
            int row = q * 32 + srow;
            __builtin_amdgcn_global_load_lds(
                (const __attribute__((address_space(1))) unsigned int*)(A + (long)(m0 + row) * K + k0 + scol),
                (__attribute__((address_space(3))) unsigned int*)&As[(q * 32 + w * 8) * 64],
                16, 0, 0);
            __builtin_amdgcn_global_load_lds(
                (const __attribute__((address_space(1))) unsigned int*)(B + (long)(n0 + row) * K + k0 + scol),
                (__attribute__((address_space(3))) unsigned int*)&Bs[(q * 32 + w * 8) * 64],
                16, 0, 0);
        }
        __syncthreads();
        #pragma unroll
        for (int kk = 0; kk < 2; kk++) {
            short8 a[4], bb[4];
            #pragma unroll
            for (int m = 0; m < 4; m++)
                a[m] = *(const short8*)&As[(wr * 64 + m * 16 + c) * 64 + kk * 32 + g * 8];
            #pragma unroll
            for (int n = 0; n < 4; n++)
                bb[n] = *(const short8*)&Bs[(wc * 64 + n * 16 + c) * 64 + kk * 32 + g * 8];
            #pragma unroll
            for (int m = 0; m < 4; m++)
                #pragma unroll
                for (int n = 0; n < 4; n++)
                    acc[m][n] = __builtin_amdgcn_mfma_f32_16x16x32_bf16(a[m], bb[n], acc[m][n], 0, 0, 0);
        }
    }

    if (md <= 1) {
        unsigned short* dst = (md == 0) ? qd : kd;
        float scale = (md == 0) ? 0.125f : 1.0f;
        #pragma unroll
        for (int m = 0; m < 4; m++) {
            #pragma unroll
            for (int r = 0; r < 4; r++) {
                int mm = m0 + wr * 64 + m * 16 + g * 4 + r;
                int bb2 = mm >> 10, ii = mm & 1023;
                #pragma unroll
                for (int n = 0; n < 4; n++) {
                    int nn = n0 + wc * 64 + n * 16 + c;
                    int hh = nn >> 6, dd = nn & 63;
                    dst[(((long)(bb2 * 16 + hh) << 10) + ii) * 64 + dd] = f2bf(acc[m][n][r] * scale);
                }
            }
        }
    } else if (md == 2) {
        #pragma unroll
        for (int m = 0; m < 4; m++) {
            int mm0 = m0 + wr * 64 + m * 16 + g * 4;
            int bb2 = mm0 >> 10, ii = mm0 & 1023;
            #pragma unroll
            for (int n = 0; n < 4; n++) {
                int nn = n0 + wc * 64 + n * 16 + c;
                int hh = nn >> 6, dd = nn & 63;
                ushort4 pkv;
                pkv.x = f2bf(acc[m][n][0]); pkv.y = f2bf(acc[m][n][1]);
                pkv.z = f2bf(acc[m][n][2]); pkv.w = f2bf(acc[m][n][3]);
                *(ushort4*)&vtd[(((long)(bb2 * 16 + hh) << 6) + dd) * 1024 + ii] = pkv;
            }
        }
    } else {
        #pragma unroll
        for (int m = 0; m < 4; m++) {
            #pragma unroll
            for (int r = 0; r < 4; r++) {
                long mm = m0 + wr * 64 + m * 16 + g * 4 + r;
                #pragma unroll
                for (int n = 0; n < 4; n++) {
                    int nn = n0 + wc * 64 + n * 16 + c;
                    outf[mm * 1024 + nn] = acc[m][n][r];
                }
            }
        }
    }
}

// ---------------- K4: flash attention, fixed-max softmax, 4-wave j-split ------
// (unchanged from round 6)
__global__ __launch_bounds__(256) void k_attn(
    const unsigned short* __restrict__ Qs, const unsigned short* __restrict__ Ks,
    const unsigned short* __restrict__ VTs, const unsigned short* __restrict__ biasg,
    unsigned short* __restrict__ Os) {
    __shared__ char smem[4 * 5632];
    int bid = blockIdx.x;
    int it = 63 - (bid >> 5);
    int bh = bid & 31;
    int b = bh >> 4, h = bh & 15;
    int w = threadIdx.x >> 6;
    int lane = threadIdx.x & 63;
    int g = lane >> 4, c = lane & 15;
    int i0 = it * 16;

    char* wbase = smem + w * 5632;
    unsigned short* p_lds = (unsigned short*)wbase;

    long plane = ((long)bh) << 16;
    const unsigned short* Qp = Qs + plane;
    const unsigned short* Kp = Ks + plane;
    const unsigned short* Vp = VTs + plane;
    const unsigned short* Bt = biasg + (((long)bh * 64 + it) << 14);

    short8 q0 = *(const short8*)(Qp + (long)(i0 + c) * 64 + g * 8);
    short8 q1 = *(const short8*)(Qp + (long)(i0 + c) * 64 + 32 + g * 8);

    f32x4 zero = {0.f, 0.f, 0.f, 0.f};
    f32x4 o[4]; o[0] = zero; o[1] = zero; o[2] = zero; o[3] = zero;
    float l[4] = {0.f, 0.f, 0.f, 0.f};

    int nj = (it >> 2) + 1;
    for (int jt = w; jt < nj; jt += 4) {
        int j0 = jt * 64;
        f32x4 s[4]; s[0] = zero; s[1] = zero; s[2] = zero; s[3] = zero;
        #pragma unroll
        for (int jj = 0; jj < 4; jj++) {
            const unsigned short* kr = Kp + (long)(j0 + jj * 16 + c) * 64 + g * 8;
            short8 ka = *(const short8*)(kr);
            short8 kb = *(const short8*)(kr + 32);
            s[jj] = __builtin_amdgcn_mfma_f32_16x16x32_bf16(q0, ka, s[jj], 0, 0, 0);
            s[jj] = __builtin_amdgcn_mfma_f32_16x16x32_bf16(q1, kb, s[jj], 0, 0, 0);
        }
        const unsigned short* bp = Bt + (jt << 10) + lane * 16;
        short8 bv0 = *(const short8*)(bp);
        short8 bv1 = *(const short8*)(bp + 8);
        #pragma unroll
        for (int r = 0; r < 4; r++) {
            #pragma unroll
            for (int jj = 0; jj < 4; jj++) {
                int idx = r * 4 + jj;
                float bb = (idx < 8) ? bf2f((unsigned short)bv0[idx])
                                     : bf2f((unsigned short)bv1[idx - 8]);
                s[jj][r] += bb;
            }
        }
        if (jt == nj - 1) {
            #pragma unroll
            for (int r = 0; r < 4; r++) {
                int i = i0 + g * 4 + r;
                #pragma unroll
                for (int jj = 0; jj < 4; jj++) {
                    if (j0 + jj * 16 + c > i) s[jj][r] = -1e9f;
                }
            }
        }
        #pragma unroll
        for (int r = 0; r < 4; r++) {
            #pragma unroll
            for (int jj = 0; jj < 4; jj++) {
                float p = exp2f(__builtin_fmaf(s[jj][r], LOG2E, -8.0f * LOG2E));
                l[r] += p;
                union { float f; unsigned int u; } pu; pu.f = p;
                p_lds[(g * 4 + r) * 72 + c + 16 * jj] = (unsigned short)(pu.u >> 16);
            }
        }
        short8 pa0 = *(const short8*)&p_lds[c * 72 + g * 8];
        short8 pa1 = *(const short8*)&p_lds[c * 72 + 32 + g * 8];
        #pragma unroll
        for (int dd = 0; dd < 4; dd++) {
            const unsigned short* vb = Vp + (long)(dd * 16 + c) * 1024 + j0 + g * 8;
            short8 v0 = *(const short8*)(vb);
            short8 v1 = *(const short8*)(vb + 32);
            o[dd] = __builtin_amdgcn_mfma_f32_16x16x32_bf16(pa0, v0, o[dd], 0, 0, 0);
            o[dd] = __builtin_amdgcn_mfma_f32_16x16x32_bf16(pa1, v1, o[dd], 0, 0, 0);
        }
    }
    float* oc = (float*)wbase;
    float* lc = (float*)(wbase + 4352);
    #pragma unroll
    for (int dd = 0; dd < 4; dd++)
        #pragma unroll
        for (int r = 0; r < 4; r++)
            oc[lane * 17 + dd * 4 + r] = o[dd][r];
    #pragma unroll
    for (int r = 0; r < 4; r++) lc[lane * 5 + r] = l[r];
    __syncthreads();

    if (w == 0) {
        float linv[4];
        #pragma unroll
        for (int r = 0; r < 4; r++) {
            float lv = 0.f;
            #pragma unroll
            for (int ww = 0; ww < 4; ww++)
                lv += ((const float*)(smem + ww * 5632 + 4352))[lane * 5 + r];
            lv += __shfl_xor(lv, 1); lv += __shfl_xor(lv, 2);
            lv += __shfl_xor(lv, 4); lv += __shfl_xor(lv, 8);
            linv[r] = 1.0f / lv;
        }
        #pragma unroll
        for (int r = 0; r < 4; r++) {
            int i = i0 + g * 4 + r;
            unsigned short* op = Os + ((long)(b * 1024 + i)) * 1024 + h * 64;
            #pragma unroll
            for (int dd = 0; dd < 4; dd++) {
                float ov = 0.f;
                #pragma unroll
                for (int ww = 0; ww < 4; ww++)
                    ov += ((const float*)(smem + ww * 5632))[lane * 17 + dd * 4 + r];
                op[dd * 16 + c] = f2bf(ov * linv[r]);
            }
        }
    }
}

// ------------------------------- launch ---------------------------------------
extern "C" void kernel_launch(void* const* d_in, const int* in_sizes, int n_in,
                              void* d_out, int out_size, void* d_ws, size_t ws_size,
                              hipStream_t stream) {
    const float* x     = (const float*)d_in[0];
    const float* Wq    = (const float*)d_in[1];
    const float* Wk    = (const float*)d_in[2];
    const float* Wv    = (const float*)d_in[3];
    const float* Wo    = (const float*)d_in[4];
    const float* Eidx  = (const float*)d_in[5];
    const float* Ebar  = (const float*)d_in[6];
    const float* Epos  = (const float*)d_in[7];
    const float* Eoct  = (const float*)d_in[8];
    const float* Esemi = (const float*)d_in[9];
    const int* barm    = (const int*)d_in[10];
    const int* posm    = (const int*)d_in[11];
    const int* octm    = (const int*)d_in[12];
    const int* semim   = (const int*)d_in[13];
    float* outf = (float*)d_out;

    unsigned short* w = (unsigned short*)d_ws;
    unsigned short* XB   = w;                   // 2M el
    unsigned short* WQB  = w + 2097152;         // 1M el each
    unsigned short* WKB  = w + 3145728;
    unsigned short* WVB  = w + 4194304;
    unsigned short* WOB  = w + 5242880;
    unsigned short* QS   = w + 6291456;         // (b,h,n,d)
    unsigned short* KS   = w + 8388608;
    unsigned short* VTS  = w + 10485760;        // (b,h,d,n)
    unsigned short* OS   = w + 12582912;        // (b,n,h*d)
    unsigned short* BIAS = w + 14680064;        // 32M el, fragment tiles

    k_convert<<<6144, 256, 0, stream>>>(x, Wq, Wk, Wv, Wo, w);
    k_bias<<<1088, 256, 0, stream>>>(Eidx, Ebar, Epos, Eoct, Esemi,
                                     barm, posm, octm, semim, BIAS);
    k_gemm<<<dim3(16, 8, 3), 256, 0, stream>>>(XB, WQB, WKB, WVB,
                                               QS, KS, VTS, nullptr, -1);
    k_attn<<<2048, 256, 0, stream>>>(QS, KS, VTS, BIAS, OS);
    k_gemm<<<dim3(16, 8, 1), 256, 0, stream>>>(OS, WOB, WOB, WOB,
                                               QS, KS, VTS, outf, 3);
}